// Round 6
// baseline (330.520 us; speedup 1.0000x reference)
//
#include <hip/hip_runtime.h>
#include <hip/hip_bf16.h>

typedef __attribute__((ext_vector_type(8))) short bf16x8;   // 8 bf16 in 4 VGPRs
typedef __attribute__((ext_vector_type(4))) float floatx4;
typedef __attribute__((ext_vector_type(16))) float floatx16;
typedef __attribute__((ext_vector_type(2))) int int2v;

#define MFMA_16x16x32(A, B, C) __builtin_amdgcn_mfma_f32_16x16x32_bf16(A, B, C, 0, 0, 0)
#define MFMA_32x32x16(A, B, C) __builtin_amdgcn_mfma_f32_32x32x16_bf16(A, B, C, 0, 0, 0)

__device__ __forceinline__ unsigned short f2b(float f) {
    __hip_bfloat16 h = __float2bfloat16(f);  // RNE
    unsigned short u;
    __builtin_memcpy(&u, &h, 2);
    return u;
}
// pack 2 floats -> 2 bf16 (RNE) in one u32 (v_cvt_pk_bf16_f32 on gfx950)
__device__ __forceinline__ unsigned pk2(float a, float b) {
    __hip_bfloat162 h = __float22bfloat162_rn(float2{a, b});
    unsigned u;
    __builtin_memcpy(&u, &h, 4);
    return u;
}
__device__ __forceinline__ bf16x8 mk8(int a, int b, int c, int d) {
    union { int u[4]; bf16x8 v; } x;
    x.u[0] = a; x.u[1] = b; x.u[2] = c; x.u[3] = d;
    return x.v;
}
__device__ __forceinline__ void async_lds16(const void* g, void* l) {
    __builtin_amdgcn_global_load_lds((__attribute__((address_space(1))) void*)g,
                                     (__attribute__((address_space(3))) void*)l, 16, 0, 0);
}

// ---------------- fp32 -> bf16 bulk convert (with per-tensor scale) ----------------
struct CvtArgs {
    const float* src[6];
    unsigned short* dst[6];
    float scale[6];
    int n8[6];
};
__global__ __launch_bounds__(256) void convert_kernel(CvtArgs a) {
    const int t = blockIdx.y;
    const int i = blockIdx.x * 256 + threadIdx.x;
    if (i >= a.n8[t]) return;
    const float sc = a.scale[t];
    const float4* s = (const float4*)a.src[t];
    const float4 x = s[2 * i], y = s[2 * i + 1];
    bf16x8 v;
    v[0] = (short)f2b(x.x * sc); v[1] = (short)f2b(x.y * sc);
    v[2] = (short)f2b(x.z * sc); v[3] = (short)f2b(x.w * sc);
    v[4] = (short)f2b(y.x * sc); v[5] = (short)f2b(y.y * sc);
    v[6] = (short)f2b(y.z * sc); v[7] = (short)f2b(y.w * sc);
    *(bf16x8*)(a.dst[t] + (size_t)i * 8) = v;
}

// ---------------- fused QKV projection GEMM: 128x128, 4 waves, XCD-swizzled ----------------
// T1 swizzle: sw = (bid%8)*64 + bid/8 -> XCD x owns sw in [64x, 64x+64): bn = x fixed,
// so each XCD's 2MB B-panel stays L2-resident while bm sweeps all of A.
// (512%8==0 -> bijective; z-offset 512 = 0 mod 8 preserves the x%8<->XCD mapping.)
struct QKVArgs {
    const unsigned short* A[3];
    const unsigned short* B[3];
    const float* bias[3];
    float bscale[3];
    unsigned short* C[3];
};
__global__ __launch_bounds__(256, 4) void gemm_qkv(QKVArgs args) {
    constexpr int M = 8192, N = 1024, K = 1024;
    __shared__ __align__(16) unsigned short As[2][4096];   // 128 x 32
    __shared__ __align__(16) unsigned short Bs[2][4096];   // 128 x 32

    const int z = blockIdx.z;
    const unsigned short* __restrict__ A = args.A[z];
    const unsigned short* __restrict__ B = args.B[z];
    const float* __restrict__ bias = args.bias[z];
    const float bsc = args.bscale[z];
    unsigned short* __restrict__ C = args.C[z];

    const int tid  = threadIdx.x;
    const int wave = tid >> 6;      // 0..3
    const int lane = tid & 63;
    const int l16  = lane & 15;
    const int quad = lane >> 4;
    const int sw = (blockIdx.x & 7) * 64 + (blockIdx.x >> 3);   // XCD-affine remap
    const int bm = (sw & 63) * 128;
    const int bn = (sw >> 6) * 128;
    const int wm = (wave >> 1) * 64;
    const int wn = (wave & 1) * 64;

    const int srow = tid >> 2;                                                // 0..63
    const int skb  = (((tid & 3) ^ ((tid >> 2) & 3) ^ ((tid >> 4) & 3)) * 8); // chunk ^ F(row)
    const int cq   = ((quad ^ (l16 & 3) ^ ((l16 >> 2) & 3)) * 8);             // read: quad ^ F(row)

    floatx4 acc[4][4] = {};

    auto stage = [&](int buf, int k0) {
        async_lds16(A + (size_t)(bm + srow) * K + skb + k0,      &As[buf][tid * 8]);
        async_lds16(A + (size_t)(bm + 64 + srow) * K + skb + k0, &As[buf][2048 + tid * 8]);
        async_lds16(B + (size_t)(bn + srow) * K + skb + k0,      &Bs[buf][tid * 8]);
        async_lds16(B + (size_t)(bn + 64 + srow) * K + skb + k0, &Bs[buf][2048 + tid * 8]);
    };

    stage(0, 0);
    for (int it = 0; it < K / 32; ++it) {
        __syncthreads();
        if (it + 1 < K / 32) stage((it + 1) & 1, (it + 1) * 32);
        const unsigned short* Ac = &As[it & 1][0];
        const unsigned short* Bc = &Bs[it & 1][0];

        bf16x8 af[4], bfr[4];
        #pragma unroll
        for (int i = 0; i < 4; ++i)
            af[i] = *(const bf16x8*)&Ac[(wm + i * 16 + l16) * 32 + cq];
        #pragma unroll
        for (int j = 0; j < 4; ++j)
            bfr[j] = *(const bf16x8*)&Bc[(wn + j * 16 + l16) * 32 + cq];
        #pragma unroll
        for (int i = 0; i < 4; ++i)
            #pragma unroll
            for (int j = 0; j < 4; ++j)
                acc[i][j] = MFMA_16x16x32(af[i], bfr[j], acc[i][j]);
    }

    if (z == 2) {
        // direct C^T b64 stores: C^T[col][row], lane's 4 acc values are consecutive rows
        #pragma unroll
        for (int j = 0; j < 4; ++j) {
            const int col = bn + wn + j * 16 + l16;
            const float bv = bias[col] * bsc;
            #pragma unroll
            for (int i = 0; i < 4; ++i) {
                uint2 w;
                w.x = pk2(acc[i][j][0] + bv, acc[i][j][1] + bv);
                w.y = pk2(acc[i][j][2] + bv, acc[i][j][3] + bv);
                const size_t off = (size_t)col * (size_t)M + (bm + wm + i * 16 + quad * 4);
                *(uint2*)&C[off] = w;
            }
        }
    } else {
        #pragma unroll
        for (int i = 0; i < 4; ++i) {
            const int row = bm + wm + i * 16 + quad * 4;
            #pragma unroll
            for (int j = 0; j < 4; ++j) {
                const int col = bn + wn + j * 16 + l16;
                const float bv = bias[col] * bsc;
                #pragma unroll
                for (int r = 0; r < 4; ++r)
                    C[(size_t)(row + r) * N + col] = f2b(acc[i][j][r] + bv);
            }
        }
    }
}

// ---------------- output projection GEMM: 128x64 tile, 4 waves, 1024 blocks ----------------
// gemm_out was the one GEMM with only 2 blocks/CU of parallelism (512 blocks vs a
// 4-resident cap). BN=64 doubles the grid to 1024 -> full 4-deep residency.
// T1 swizzle: sw = (bid%8)*128 + bid/8 -> each XCD owns 2 adjacent 64-col B panels.
__global__ __launch_bounds__(256, 4) void gemm_out(
    const unsigned short* __restrict__ A, const unsigned short* __restrict__ B,
    const float* __restrict__ bias, float* __restrict__ C,
    int M, int N, int K)
{
    __shared__ __align__(16) unsigned short As[2][4096];   // 128 x 32
    __shared__ __align__(16) unsigned short Bs[2][2048];   // 64 x 32

    const int tid  = threadIdx.x;
    const int wave = tid >> 6;
    const int lane = tid & 63;
    const int l16  = lane & 15;
    const int quad = lane >> 4;
    const int sw = (blockIdx.x & 7) * 128 + (blockIdx.x >> 3);
    const int bm = (sw & 63) * 128;
    const int bn = (sw >> 6) * 64;
    const int wm = (wave >> 1) * 64;
    const int wn = (wave & 1) * 32;

    const int srow = tid >> 2;
    const int skb  = (((tid & 3) ^ ((tid >> 2) & 3) ^ ((tid >> 4) & 3)) * 8);
    const int cq   = ((quad ^ (l16 & 3) ^ ((l16 >> 2) & 3)) * 8);

    floatx4 acc[4][2] = {};

    auto stage = [&](int buf, int k0) {
        async_lds16(A + (size_t)(bm + srow) * K + skb + k0,      &As[buf][tid * 8]);
        async_lds16(A + (size_t)(bm + 64 + srow) * K + skb + k0, &As[buf][2048 + tid * 8]);
        async_lds16(B + (size_t)(bn + srow) * K + skb + k0,      &Bs[buf][tid * 8]);
    };

    stage(0, 0);
    for (int it = 0; it < K / 32; ++it) {
        __syncthreads();
        if (it + 1 < K / 32) stage((it + 1) & 1, (it + 1) * 32);
        const unsigned short* Ac = &As[it & 1][0];
        const unsigned short* Bc = &Bs[it & 1][0];

        bf16x8 af[4], bfr[2];
        #pragma unroll
        for (int i = 0; i < 4; ++i)
            af[i] = *(const bf16x8*)&Ac[(wm + i * 16 + l16) * 32 + cq];
        #pragma unroll
        for (int j = 0; j < 2; ++j)
            bfr[j] = *(const bf16x8*)&Bc[(wn + j * 16 + l16) * 32 + cq];
        #pragma unroll
        for (int i = 0; i < 4; ++i)
            #pragma unroll
            for (int j = 0; j < 2; ++j)
                acc[i][j] = MFMA_16x16x32(af[i], bfr[j], acc[i][j]);
    }

    #pragma unroll
    for (int i = 0; i < 4; ++i) {
        const int row = bm + wm + i * 16 + quad * 4;
        #pragma unroll
        for (int j = 0; j < 2; ++j) {
            const int col = bn + wn + j * 16 + l16;
            const float bv = bias[col];
            #pragma unroll
            for (int r = 0; r < 4; ++r)
                C[(size_t)(row + r) * N + col] = acc[i][j][r] + bv;
        }
    }
}

// ---------------- flash attention v10 (unchanged control): 32x32 MFMA, in-reg P ----------
__global__ __launch_bounds__(256, 4) void attn_kernel(
    const unsigned short* __restrict__ Q, const unsigned short* __restrict__ Kg,
    const unsigned short* __restrict__ Vt, unsigned short* __restrict__ Y)
{
    __shared__ __align__(16) unsigned short Ks[2][4096];   // swizzled [kv(64)][d(64)]
    __shared__ __align__(16) unsigned short Vs[2][4096];   // swizzled [d(64)][kv(64)]

    const int tid  = threadIdx.x;
    const int wave = tid >> 6;      // 0..3
    const int lane = tid & 63;
    const int l31  = lane & 31;
    const int hi   = lane >> 5;     // 0/1
    const int x7   = lane & 7;
    const int h4   = ((lane >> 4) & 1) << 2;
    const int bh = blockIdx.x & 63;
    const int qt = blockIdx.x >> 6;
    const int b  = bh >> 4;
    const int h  = bh & 15;
    const int q0 = qt * 128 + wave * 32;
    const size_t base  = ((size_t)b * 2048) * 1024 + (size_t)h * 64;
    const size_t vbase = ((size_t)h * 64) * 8192 + (size_t)b * 2048;

    bf16x8 qf[4];
    {
        const size_t qrow = base + (size_t)(q0 + l31) * 1024 + hi * 8;
        #pragma unroll
        for (int ks = 0; ks < 4; ++ks)
            qf[ks] = *(const bf16x8*)&Q[qrow + ks * 16];
    }

    bf16x8 ones;
    #pragma unroll
    for (int e = 0; e < 8; ++e) ones[e] = (short)0x3F80;   // bf16 1.0
    const floatx16 Z16 = {0.f,0.f,0.f,0.f,0.f,0.f,0.f,0.f,
                          0.f,0.f,0.f,0.f,0.f,0.f,0.f,0.f};

    floatx16 o0 = Z16, o1 = Z16;
    floatx16 rs = Z16;

    const int r0  = tid >> 3;
    const int csw = (tid & 7) ^ (r0 & 7) ^ (((tid >> 7) & 1) << 2);

    int co[4];
    #pragma unroll
    for (int ks = 0; ks < 4; ++ks) co[ks] = (((ks * 2 + hi) ^ x7 ^ h4) * 8);
    const int krow = l31 * 64;

    auto stage = [&](int buf, int kv0) {
        async_lds16(&Kg[base + (size_t)(kv0 + r0) * 1024 + csw * 8],      &Ks[buf][tid * 8]);
        async_lds16(&Kg[base + (size_t)(kv0 + 32 + r0) * 1024 + csw * 8], &Ks[buf][2048 + tid * 8]);
        async_lds16(&Vt[vbase + (size_t)r0 * 8192 + kv0 + csw * 8],        &Vs[buf][tid * 8]);
        async_lds16(&Vt[vbase + (size_t)(r0 + 32) * 8192 + kv0 + csw * 8], &Vs[buf][2048 + tid * 8]);
    };

    auto procP = [&](const floatx16& st, bf16x8& paA, bf16x8& paB) {
        float e[16];
        #pragma unroll
        for (int i = 0; i < 16; ++i) e[i] = __builtin_amdgcn_exp2f(st[i]);
        const int w0 = (int)pk2(e[0],  e[1]);
        const int w1 = (int)pk2(e[2],  e[3]);
        const int w2 = (int)pk2(e[4],  e[5]);
        const int w3 = (int)pk2(e[6],  e[7]);
        const int w4 = (int)pk2(e[8],  e[9]);
        const int w5 = (int)pk2(e[10], e[11]);
        const int w6 = (int)pk2(e[12], e[13]);
        const int w7 = (int)pk2(e[14], e[15]);
        const int2v a0 = __builtin_amdgcn_permlane32_swap(w0, w2, false, false);
        const int2v a1 = __builtin_amdgcn_permlane32_swap(w1, w3, false, false);
        const int2v a2 = __builtin_amdgcn_permlane32_swap(w4, w6, false, false);
        const int2v a3 = __builtin_amdgcn_permlane32_swap(w5, w7, false, false);
        paA = mk8(a0.x, a1.x, a0.y, a1.y);
        paB = mk8(a2.x, a3.x, a2.y, a3.y);
    };

    stage(0, 0);
    for (int t = 0; t < 32; ++t) {
        __syncthreads();
        if (t < 31) stage((t + 1) & 1, (t + 1) * 64);
        const unsigned short* Kc = &Ks[t & 1][0];
        const unsigned short* Vc = &Vs[t & 1][0];

        floatx16 st0 = Z16, st1 = Z16;
        __builtin_amdgcn_s_setprio(1);
        #pragma unroll
        for (int ks = 0; ks < 4; ++ks) {
            const bf16x8 kf0 = *(const bf16x8*)&Kc[krow + co[ks]];
            const bf16x8 kf1 = *(const bf16x8*)&Kc[2048 + krow + co[ks]];
            st0 = MFMA_32x32x16(kf0, qf[ks], st0);
            st1 = MFMA_32x32x16(kf1, qf[ks], st1);
        }
        __builtin_amdgcn_s_setprio(0);

        bf16x8 pa[4];
        procP(st0, pa[0], pa[1]);
        procP(st1, pa[2], pa[3]);

        __builtin_amdgcn_s_setprio(1);
        #pragma unroll
        for (int f = 0; f < 4; ++f) {
            const bf16x8 v0 = *(const bf16x8*)&Vc[krow + co[f]];
            const bf16x8 v1 = *(const bf16x8*)&Vc[2048 + krow + co[f]];
            o0 = MFMA_32x32x16(pa[f], v0, o0);
            o1 = MFMA_32x32x16(pa[f], v1, o1);
            rs = MFMA_32x32x16(pa[f], ones, rs);
        }
        __builtin_amdgcn_s_setprio(0);
    }

    #pragma unroll
    for (int g = 0; g < 4; ++g) {
        #pragma unroll
        for (int e2 = 0; e2 < 4; ++e2) {
            const int reg = g * 4 + e2;
            const float inv = 1.0f / rs[reg];
            const size_t row = q0 + 8 * g + 4 * hi + e2;
            Y[base + row * 1024 + l31]      = f2b(o0[reg] * inv);
            Y[base + row * 1024 + 32 + l31] = f2b(o1[reg] * inv);
        }
    }
}

extern "C" void kernel_launch(void* const* d_in, const int* in_sizes, int n_in,
                              void* d_out, int out_size, void* d_ws, size_t ws_size,
                              hipStream_t stream)
{
    const float* dec = (const float*)d_in[0];
    const float* enc = (const float*)d_in[1];
    const float* Wq  = (const float*)d_in[2];
    const float* bq  = (const float*)d_in[3];
    const float* Wk  = (const float*)d_in[4];
    const float* bk  = (const float*)d_in[5];
    const float* Wv  = (const float*)d_in[6];
    const float* bv  = (const float*)d_in[7];
    const float* Wp  = (const float*)d_in[8];
    const float* bp  = (const float*)d_in[9];

    const size_t NTOK = 8192, DM = 1024;
    unsigned short* ws = (unsigned short*)d_ws;
    unsigned short* decB = ws;
    unsigned short* encB = decB + NTOK * DM;
    unsigned short* WqB  = encB + NTOK * DM;
    unsigned short* WkB  = WqB + DM * DM;
    unsigned short* WvB  = WkB + DM * DM;
    unsigned short* WpB  = WvB + DM * DM;
    unsigned short* Qb   = WpB + DM * DM;
    unsigned short* Kb   = Qb + NTOK * DM;
    unsigned short* VtG  = Kb + NTOK * DM;           // [1024][8192]
    unsigned short* Yb   = VtG + NTOK * DM;

    const float C_SM = 0.18033688f;   // log2(e) / sqrt(64)

    CvtArgs a;
    a.src[0] = dec; a.src[1] = enc; a.src[2] = Wq; a.src[3] = Wk; a.src[4] = Wv; a.src[5] = Wp;
    a.dst[0] = decB; a.dst[1] = encB; a.dst[2] = WqB; a.dst[3] = WkB; a.dst[4] = WvB; a.dst[5] = WpB;
    a.scale[0] = 1.f; a.scale[1] = 1.f; a.scale[2] = C_SM;
    a.scale[3] = 1.f; a.scale[4] = 1.f; a.scale[5] = 1.f;
    a.n8[0] = a.n8[1] = (int)(NTOK * DM / 8);
    a.n8[2] = a.n8[3] = a.n8[4] = a.n8[5] = (int)(DM * DM / 8);
    convert_kernel<<<dim3(4096, 6), 256, 0, stream>>>(a);

    QKVArgs qa;
    qa.A[0] = decB; qa.A[1] = encB; qa.A[2] = encB;
    qa.B[0] = WqB;  qa.B[1] = WkB;  qa.B[2] = WvB;
    qa.bias[0] = bq; qa.bias[1] = bk; qa.bias[2] = bv;
    qa.bscale[0] = C_SM; qa.bscale[1] = 1.f; qa.bscale[2] = 1.f;
    qa.C[0] = Qb;   qa.C[1] = Kb;   qa.C[2] = VtG;
    gemm_qkv<<<dim3(512, 1, 3), 256, 0, stream>>>(qa);

    attn_kernel<<<dim3(1024), 256, 0, stream>>>(Qb, Kb, VtG, Yb);
    gemm_out<<<dim3(1024), 256, 0, stream>>>(Yb, WpB, bp, (float*)d_out, 8192, 1024, 1024);
}

// Round 7
// 315.174 us; speedup vs baseline: 1.0487x; 1.0487x over previous
//
#include <hip/hip_runtime.h>
#include <hip/hip_bf16.h>

typedef __attribute__((ext_vector_type(8))) short bf16x8;   // 8 bf16 in 4 VGPRs
typedef __attribute__((ext_vector_type(4))) float floatx4;
typedef __attribute__((ext_vector_type(16))) float floatx16;
typedef __attribute__((ext_vector_type(2))) int int2v;

#define MFMA_16x16x32(A, B, C) __builtin_amdgcn_mfma_f32_16x16x32_bf16(A, B, C, 0, 0, 0)
#define MFMA_32x32x16(A, B, C) __builtin_amdgcn_mfma_f32_32x32x16_bf16(A, B, C, 0, 0, 0)

__device__ __forceinline__ unsigned short f2b(float f) {
    __hip_bfloat16 h = __float2bfloat16(f);  // RNE
    unsigned short u;
    __builtin_memcpy(&u, &h, 2);
    return u;
}
// pack 2 floats -> 2 bf16 (RNE) in one u32 (v_cvt_pk_bf16_f32 on gfx950)
__device__ __forceinline__ unsigned pk2(float a, float b) {
    __hip_bfloat162 h = __float22bfloat162_rn(float2{a, b});
    unsigned u;
    __builtin_memcpy(&u, &h, 4);
    return u;
}
__device__ __forceinline__ bf16x8 mk8(int a, int b, int c, int d) {
    union { int u[4]; bf16x8 v; } x;
    x.u[0] = a; x.u[1] = b; x.u[2] = c; x.u[3] = d;
    return x.v;
}
__device__ __forceinline__ void async_lds16(const void* g, void* l) {
    __builtin_amdgcn_global_load_lds((__attribute__((address_space(1))) void*)g,
                                     (__attribute__((address_space(3))) void*)l, 16, 0, 0);
}

// ---------------- fp32 -> bf16 bulk convert (with per-tensor scale) ----------------
struct CvtArgs {
    const float* src[6];
    unsigned short* dst[6];
    float scale[6];
    int n8[6];
};
__global__ __launch_bounds__(256) void convert_kernel(CvtArgs a) {
    const int t = blockIdx.y;
    const int i = blockIdx.x * 256 + threadIdx.x;
    if (i >= a.n8[t]) return;
    const float sc = a.scale[t];
    const float4* s = (const float4*)a.src[t];
    const float4 x = s[2 * i], y = s[2 * i + 1];
    bf16x8 v;
    v[0] = (short)f2b(x.x * sc); v[1] = (short)f2b(x.y * sc);
    v[2] = (short)f2b(x.z * sc); v[3] = (short)f2b(x.w * sc);
    v[4] = (short)f2b(y.x * sc); v[5] = (short)f2b(y.y * sc);
    v[6] = (short)f2b(y.z * sc); v[7] = (short)f2b(y.w * sc);
    *(bf16x8*)(a.dst[t] + (size_t)i * 8) = v;
}

// ---------------- fused QKV projection GEMM: 128x128, 4 waves, 4 blocks/CU (R5 config) ----
struct QKVArgs {
    const unsigned short* A[3];
    const unsigned short* B[3];
    const float* bias[3];
    float bscale[3];
    unsigned short* C[3];
};
__global__ __launch_bounds__(256, 4) void gemm_qkv(QKVArgs args) {
    constexpr int M = 8192, N = 1024, K = 1024;
    __shared__ __align__(16) unsigned short As[2][4096];   // 128 x 32
    __shared__ __align__(16) unsigned short Bs[2][4096];   // 128 x 32

    const int z = blockIdx.z;
    const unsigned short* __restrict__ A = args.A[z];
    const unsigned short* __restrict__ B = args.B[z];
    const float* __restrict__ bias = args.bias[z];
    const float bsc = args.bscale[z];
    unsigned short* __restrict__ C = args.C[z];

    const int tid  = threadIdx.x;
    const int wave = tid >> 6;      // 0..3
    const int lane = tid & 63;
    const int l16  = lane & 15;
    const int quad = lane >> 4;
    const int bm = (blockIdx.x & 63) * 128;
    const int bn = (blockIdx.x >> 6) * 128;
    const int wm = (wave >> 1) * 64;
    const int wn = (wave & 1) * 64;

    const int srow = tid >> 2;                                                // 0..63
    const int skb  = (((tid & 3) ^ ((tid >> 2) & 3) ^ ((tid >> 4) & 3)) * 8); // chunk ^ F(row)
    const int cq   = ((quad ^ (l16 & 3) ^ ((l16 >> 2) & 3)) * 8);             // read: quad ^ F(row)

    floatx4 acc[4][4] = {};

    auto stage = [&](int buf, int k0) {
        async_lds16(A + (size_t)(bm + srow) * K + skb + k0,      &As[buf][tid * 8]);
        async_lds16(A + (size_t)(bm + 64 + srow) * K + skb + k0, &As[buf][2048 + tid * 8]);
        async_lds16(B + (size_t)(bn + srow) * K + skb + k0,      &Bs[buf][tid * 8]);
        async_lds16(B + (size_t)(bn + 64 + srow) * K + skb + k0, &Bs[buf][2048 + tid * 8]);
    };

    stage(0, 0);
    for (int it = 0; it < K / 32; ++it) {
        __syncthreads();
        if (it + 1 < K / 32) stage((it + 1) & 1, (it + 1) * 32);
        const unsigned short* Ac = &As[it & 1][0];
        const unsigned short* Bc = &Bs[it & 1][0];

        bf16x8 af[4], bfr[4];
        #pragma unroll
        for (int i = 0; i < 4; ++i)
            af[i] = *(const bf16x8*)&Ac[(wm + i * 16 + l16) * 32 + cq];
        #pragma unroll
        for (int j = 0; j < 4; ++j)
            bfr[j] = *(const bf16x8*)&Bc[(wn + j * 16 + l16) * 32 + cq];
        #pragma unroll
        for (int i = 0; i < 4; ++i)
            #pragma unroll
            for (int j = 0; j < 4; ++j)
                acc[i][j] = MFMA_16x16x32(af[i], bfr[j], acc[i][j]);
    }

    if (z == 2) {
        // direct C^T b64 stores: C^T[col][row], lane's 4 acc values are consecutive rows
        #pragma unroll
        for (int j = 0; j < 4; ++j) {
            const int col = bn + wn + j * 16 + l16;
            const float bv = bias[col] * bsc;
            #pragma unroll
            for (int i = 0; i < 4; ++i) {
                uint2 w;
                w.x = pk2(acc[i][j][0] + bv, acc[i][j][1] + bv);
                w.y = pk2(acc[i][j][2] + bv, acc[i][j][3] + bv);
                const size_t off = (size_t)col * (size_t)M + (bm + wm + i * 16 + quad * 4);
                *(uint2*)&C[off] = w;
            }
        }
    } else {
        #pragma unroll
        for (int i = 0; i < 4; ++i) {
            const int row = bm + wm + i * 16 + quad * 4;
            #pragma unroll
            for (int j = 0; j < 4; ++j) {
                const int col = bn + wn + j * 16 + l16;
                const float bv = bias[col] * bsc;
                #pragma unroll
                for (int r = 0; r < 4; ++r)
                    C[(size_t)(row + r) * N + col] = f2b(acc[i][j][r] + bv);
            }
        }
    }
}

// ---------------- output projection GEMM: 128x128, 4 waves, 4 blocks/CU (R5 config) --------
__global__ __launch_bounds__(256, 4) void gemm_out(
    const unsigned short* __restrict__ A, const unsigned short* __restrict__ B,
    const float* __restrict__ bias, float* __restrict__ C,
    int M, int N, int K)
{
    __shared__ __align__(16) unsigned short As[2][4096];
    __shared__ __align__(16) unsigned short Bs[2][4096];

    const int tid  = threadIdx.x;
    const int wave = tid >> 6;
    const int lane = tid & 63;
    const int l16  = lane & 15;
    const int quad = lane >> 4;
    const int bm = (blockIdx.x & 63) * 128;
    const int bn = (blockIdx.x >> 6) * 128;
    const int wm = (wave >> 1) * 64;
    const int wn = (wave & 1) * 64;

    const int srow = tid >> 2;
    const int skb  = (((tid & 3) ^ ((tid >> 2) & 3) ^ ((tid >> 4) & 3)) * 8);
    const int cq   = ((quad ^ (l16 & 3) ^ ((l16 >> 2) & 3)) * 8);

    floatx4 acc[4][4] = {};

    auto stage = [&](int buf, int k0) {
        async_lds16(A + (size_t)(bm + srow) * K + skb + k0,      &As[buf][tid * 8]);
        async_lds16(A + (size_t)(bm + 64 + srow) * K + skb + k0, &As[buf][2048 + tid * 8]);
        async_lds16(B + (size_t)(bn + srow) * K + skb + k0,      &Bs[buf][tid * 8]);
        async_lds16(B + (size_t)(bn + 64 + srow) * K + skb + k0, &Bs[buf][2048 + tid * 8]);
    };

    stage(0, 0);
    for (int it = 0; it < K / 32; ++it) {
        __syncthreads();
        if (it + 1 < K / 32) stage((it + 1) & 1, (it + 1) * 32);
        const unsigned short* Ac = &As[it & 1][0];
        const unsigned short* Bc = &Bs[it & 1][0];

        bf16x8 af[4], bfr[4];
        #pragma unroll
        for (int i = 0; i < 4; ++i)
            af[i] = *(const bf16x8*)&Ac[(wm + i * 16 + l16) * 32 + cq];
        #pragma unroll
        for (int j = 0; j < 4; ++j)
            bfr[j] = *(const bf16x8*)&Bc[(wn + j * 16 + l16) * 32 + cq];
        #pragma unroll
        for (int i = 0; i < 4; ++i)
            #pragma unroll
            for (int j = 0; j < 4; ++j)
                acc[i][j] = MFMA_16x16x32(af[i], bfr[j], acc[i][j]);
    }

    #pragma unroll
    for (int i = 0; i < 4; ++i) {
        const int row = bm + wm + i * 16 + quad * 4;
        #pragma unroll
        for (int j = 0; j < 4; ++j) {
            const int col = bn + wn + j * 16 + l16;
            const float bv = bias[col];
            #pragma unroll
            for (int r = 0; r < 4; ++r)
                C[(size_t)(row + r) * N + col] = acc[i][j][r] + bv;
        }
    }
}

// ---------------- flash attention v11: chunk-major LDS (conflict-free b128 reads) ----------
// Root cause of the invariant 8.39M conflicts: fragment reads had 32 lanes at row-stride
// 128B (= full bank wrap) with only 8 16B-slots per window -> structural 4-way conflict,
// immune to chunk-XOR. Fix: LDS layout [half][chunk(8)][row(32)][16B] -> read addr
// half*2048 + chunk*256 + l31*8 elems: 32 consecutive 16B slots = conflict-free.
// Realized by pre-permuting the STAGING SOURCE only (dest stays linear tid*16):
// staging thread tid loads (row = tid&31, chunk = tid>>5). Cost: 32B-granule source
// scatter (2x L2 sector amplification), L2-resident + hidden by 1-tile prefetch.
__global__ __launch_bounds__(256, 4) void attn_kernel(
    const unsigned short* __restrict__ Q, const unsigned short* __restrict__ Kg,
    const unsigned short* __restrict__ Vt, unsigned short* __restrict__ Y)
{
    __shared__ __align__(16) unsigned short Ks[2][4096];   // [half kv][chunk d][row kv][8]
    __shared__ __align__(16) unsigned short Vs[2][4096];   // [half d][chunk kv][row d][8]

    const int tid  = threadIdx.x;
    const int wave = tid >> 6;      // 0..3
    const int lane = tid & 63;
    const int l31  = lane & 31;
    const int hi   = lane >> 5;     // 0/1
    const int bh = blockIdx.x & 63;
    const int qt = blockIdx.x >> 6;
    const int b  = bh >> 4;
    const int h  = bh & 15;
    const int q0 = qt * 128 + wave * 32;
    const size_t base  = ((size_t)b * 2048) * 1024 + (size_t)h * 64;
    const size_t vbase = ((size_t)h * 64) * 8192 + (size_t)b * 2048;

    // Q fragments (B-operand, 32x32x16): qf[ks] = Q[q0 + l31][d = ks*16 + hi*8 .. +8]
    bf16x8 qf[4];
    {
        const size_t qrow = base + (size_t)(q0 + l31) * 1024 + hi * 8;
        #pragma unroll
        for (int ks = 0; ks < 4; ++ks)
            qf[ks] = *(const bf16x8*)&Q[qrow + ks * 16];
    }

    bf16x8 ones;
    #pragma unroll
    for (int e = 0; e < 8; ++e) ones[e] = (short)0x3F80;   // bf16 1.0
    const floatx16 Z16 = {0.f,0.f,0.f,0.f,0.f,0.f,0.f,0.f,
                          0.f,0.f,0.f,0.f,0.f,0.f,0.f,0.f};

    floatx16 o0 = Z16, o1 = Z16;    // O[q rows][d = blk*32 + l31]
    floatx16 rs = Z16;              // rowsum via ones-MFMA; same C-layout as o

    // staging source permutation: thread tid -> (row = tid&31, 16B-chunk = tid>>5)
    const int sr = tid & 31;
    const int sc8 = (tid >> 5) * 8;   // chunk offset in elements

    // hoisted conflict-free read base (elements): chunk-major
    const int rb = hi * 256 + l31 * 8;

    auto stage = [&](int buf, int kv0) {
        async_lds16(&Kg[base + (size_t)(kv0 + sr) * 1024 + sc8],       &Ks[buf][tid * 8]);
        async_lds16(&Kg[base + (size_t)(kv0 + 32 + sr) * 1024 + sc8],  &Ks[buf][2048 + tid * 8]);
        async_lds16(&Vt[vbase + (size_t)sr * 8192 + kv0 + sc8],        &Vs[buf][tid * 8]);
        async_lds16(&Vt[vbase + (size_t)(sr + 32) * 8192 + kv0 + sc8], &Vs[buf][2048 + tid * 8]);
    };

    // exp2 + pack + permlane transpose: st (D: col q=l31, 16 kv rows) -> 2 A-fragments
    auto procP = [&](const floatx16& st, bf16x8& paA, bf16x8& paB) {
        float e[16];
        #pragma unroll
        for (int i = 0; i < 16; ++i) e[i] = __builtin_amdgcn_exp2f(st[i]);
        const int w0 = (int)pk2(e[0],  e[1]);
        const int w1 = (int)pk2(e[2],  e[3]);
        const int w2 = (int)pk2(e[4],  e[5]);
        const int w3 = (int)pk2(e[6],  e[7]);
        const int w4 = (int)pk2(e[8],  e[9]);
        const int w5 = (int)pk2(e[10], e[11]);
        const int w6 = (int)pk2(e[12], e[13]);
        const int w7 = (int)pk2(e[14], e[15]);
        const int2v a0 = __builtin_amdgcn_permlane32_swap(w0, w2, false, false);
        const int2v a1 = __builtin_amdgcn_permlane32_swap(w1, w3, false, false);
        const int2v a2 = __builtin_amdgcn_permlane32_swap(w4, w6, false, false);
        const int2v a3 = __builtin_amdgcn_permlane32_swap(w5, w7, false, false);
        paA = mk8(a0.x, a1.x, a0.y, a1.y);
        paB = mk8(a2.x, a3.x, a2.y, a3.y);
    };

    stage(0, 0);
    for (int t = 0; t < 32; ++t) {
        __syncthreads();
        if (t < 31) stage((t + 1) & 1, (t + 1) * 64);
        const unsigned short* Kc = &Ks[t & 1][0];
        const unsigned short* Vc = &Vs[t & 1][0];

        // ---- S^T = K Q^T : 2 kv-blocks x 4 d-steps of 32x32x16 ----
        floatx16 st0 = Z16, st1 = Z16;
        __builtin_amdgcn_s_setprio(1);
        #pragma unroll
        for (int ks = 0; ks < 4; ++ks) {
            const bf16x8 kf0 = *(const bf16x8*)&Kc[rb + ks * 512];
            const bf16x8 kf1 = *(const bf16x8*)&Kc[2048 + rb + ks * 512];
            st0 = MFMA_32x32x16(kf0, qf[ks], st0);
            st1 = MFMA_32x32x16(kf1, qf[ks], st1);
        }
        __builtin_amdgcn_s_setprio(0);

        // ---- P = 2^S^T, transpose to A-fragments in registers ----
        bf16x8 pa[4];
        procP(st0, pa[0], pa[1]);
        procP(st1, pa[2], pa[3]);

        // ---- O += P V ; rowsum += P @ ones (matrix pipe) ----
        __builtin_amdgcn_s_setprio(1);
        #pragma unroll
        for (int f = 0; f < 4; ++f) {
            const bf16x8 v0 = *(const bf16x8*)&Vc[rb + f * 512];
            const bf16x8 v1 = *(const bf16x8*)&Vc[2048 + rb + f * 512];
            o0 = MFMA_32x32x16(pa[f], v0, o0);
            o1 = MFMA_32x32x16(pa[f], v1, o1);
            rs = MFMA_32x32x16(pa[f], ones, rs);
        }
        __builtin_amdgcn_s_setprio(0);
    }

    #pragma unroll
    for (int g = 0; g < 4; ++g) {
        #pragma unroll
        for (int e2 = 0; e2 < 4; ++e2) {
            const int reg = g * 4 + e2;
            const float inv = 1.0f / rs[reg];
            const size_t row = q0 + 8 * g + 4 * hi + e2;
            Y[base + row * 1024 + l31]      = f2b(o0[reg] * inv);
            Y[base + row * 1024 + 32 + l31] = f2b(o1[reg] * inv);
        }
    }
}

extern "C" void kernel_launch(void* const* d_in, const int* in_sizes, int n_in,
                              void* d_out, int out_size, void* d_ws, size_t ws_size,
                              hipStream_t stream)
{
    const float* dec = (const float*)d_in[0];
    const float* enc = (const float*)d_in[1];
    const float* Wq  = (const float*)d_in[2];
    const float* bq  = (const float*)d_in[3];
    const float* Wk  = (const float*)d_in[4];
    const float* bk  = (const float*)d_in[5];
    const float* Wv  = (const float*)d_in[6];
    const float* bv  = (const float*)d_in[7];
    const float* Wp  = (const float*)d_in[8];
    const float* bp  = (const float*)d_in[9];

    const size_t NTOK = 8192, DM = 1024;
    unsigned short* ws = (unsigned short*)d_ws;
    unsigned short* decB = ws;
    unsigned short* encB = decB + NTOK * DM;
    unsigned short* WqB  = encB + NTOK * DM;
    unsigned short* WkB  = WqB + DM * DM;
    unsigned short* WvB  = WkB + DM * DM;
    unsigned short* WpB  = WvB + DM * DM;
    unsigned short* Qb   = WpB + DM * DM;
    unsigned short* Kb   = Qb + NTOK * DM;
    unsigned short* VtG  = Kb + NTOK * DM;           // [1024][8192]
    unsigned short* Yb   = VtG + NTOK * DM;

    const float C_SM = 0.18033688f;   // log2(e) / sqrt(64)

    CvtArgs a;
    a.src[0] = dec; a.src[1] = enc; a.src[2] = Wq; a.src[3] = Wk; a.src[4] = Wv; a.src[5] = Wp;
    a.dst[0] = decB; a.dst[1] = encB; a.dst[2] = WqB; a.dst[3] = WkB; a.dst[4] = WvB; a.dst[5] = WpB;
    a.scale[0] = 1.f; a.scale[1] = 1.f; a.scale[2] = C_SM;
    a.scale[3] = 1.f; a.scale[4] = 1.f; a.scale[5] = 1.f;
    a.n8[0] = a.n8[1] = (int)(NTOK * DM / 8);
    a.n8[2] = a.n8[3] = a.n8[4] = a.n8[5] = (int)(DM * DM / 8);
    convert_kernel<<<dim3(4096, 6), 256, 0, stream>>>(a);

    QKVArgs qa;
    qa.A[0] = decB; qa.A[1] = encB; qa.A[2] = encB;
    qa.B[0] = WqB;  qa.B[1] = WkB;  qa.B[2] = WvB;
    qa.bias[0] = bq; qa.bias[1] = bk; qa.bias[2] = bv;
    qa.bscale[0] = C_SM; qa.bscale[1] = 1.f; qa.bscale[2] = 1.f;
    qa.C[0] = Qb;   qa.C[1] = Kb;   qa.C[2] = VtG;
    gemm_qkv<<<dim3(512, 1, 3), 256, 0, stream>>>(qa);

    attn_kernel<<<dim3(1024), 256, 0, stream>>>(Qb, Kb, VtG, Yb);
    gemm_out<<<dim3(512), 256, 0, stream>>>(Yb, WpB, bp, (float*)d_out, 8192, 1024, 1024);
}